// Round 3
// baseline (554.798 us; speedup 1.0000x reference)
//
#include <hip/hip_runtime.h>

// ---------------------------------------------------------------------------
// Attention_73813307949177
//   kx = k Wk^T + bk ; qx = q Wq^T + bq
//   score = softmax2(softmax1(qx kx^T + bias)*wei + bias)
//   out = (score kx) Wp^T + bp
// Outputs (concat): out [4096,1024] fp32, score [4096,4096] fp32
//
// R2 -> R3:
//  * MFMA core 16x16x32 -> 32x32x16 (half the MFMA issue slots per FLOP,
//    +15% measured ceiling). C/D: col=lane&31, row=(reg&3)+8*(reg>>2)+4*(lane>>5).
//  * proj: batched z=2, NO split-K, direct bias+hi/lo epilogue (kills 100MB
//    partial traffic + 2 reduces).
//  * out: split-K 4 -> 2. prep kernels merged 5 -> 2 launches.
// ---------------------------------------------------------------------------

typedef __bf16 bf16;
typedef __bf16 bf16x8 __attribute__((ext_vector_type(8)));
typedef __bf16 bf16x4 __attribute__((ext_vector_type(4)));
typedef float  f32x4  __attribute__((ext_vector_type(4)));
typedef float  f32x16 __attribute__((ext_vector_type(16)));

typedef __attribute__((address_space(1))) void as1_void;
typedef __attribute__((address_space(3))) void as3_void;

#define NQ  4096
#define NKK 4096
#define EMB 1024

#define BM 128
#define BN 128
#define BK 32

__device__ __forceinline__ void gld_lds16(const void* g, void* l) {
    __builtin_amdgcn_global_load_lds((as1_void*)g, (as3_void*)l, 16, 0, 0);
}

// ---------------------------------------------------------------------------
// prep: fp32 -> bf16 hi/lo split, two tensors batched via blockIdx.y
__global__ __launch_bounds__(256) void prep_pair(
    const float* __restrict__ a, const float* __restrict__ b,
    bf16* __restrict__ ah, bf16* __restrict__ al,
    bf16* __restrict__ bh, bf16* __restrict__ bl, int n)
{
    const float* s = blockIdx.y ? b : a;
    bf16* h = blockIdx.y ? bh : ah;
    bf16* l = blockIdx.y ? bl : al;
    const int i = (blockIdx.x * 256 + threadIdx.x) * 4;
    if (i >= n) return;
    f32x4 v = *(const f32x4*)(s + i);
    bf16x4 hv, lv;
#pragma unroll
    for (int c = 0; c < 4; c++) {
        float x = v[c];
        bf16 hh = (bf16)x;
        hv[c] = hh;
        lv[c] = (bf16)(x - (float)hh);
    }
    *(bf16x4*)(h + i) = hv;
    *(bf16x4*)(l + i) = lv;
}

// three weight matrices batched via blockIdx.y (Wp's lo goes to scratch)
__global__ __launch_bounds__(256) void prep_w3(
    const float* __restrict__ w0, const float* __restrict__ w1, const float* __restrict__ w2,
    bf16* __restrict__ h0, bf16* __restrict__ l0,
    bf16* __restrict__ h1, bf16* __restrict__ l1,
    bf16* __restrict__ h2, bf16* __restrict__ l2, int n)
{
    const int z = blockIdx.y;
    const float* s = (z == 0) ? w0 : (z == 1) ? w1 : w2;
    bf16* h = (z == 0) ? h0 : (z == 1) ? h1 : h2;
    bf16* l = (z == 0) ? l0 : (z == 1) ? l1 : l2;
    const int i = (blockIdx.x * 256 + threadIdx.x) * 4;
    if (i >= n) return;
    f32x4 v = *(const f32x4*)(s + i);
    bf16x4 hv, lv;
#pragma unroll
    for (int c = 0; c < 4; c++) {
        float x = v[c];
        bf16 hh = (bf16)x;
        hv[c] = hh;
        lv[c] = (bf16)(x - (float)hh);
    }
    *(bf16x4*)(h + i) = hv;
    *(bf16x4*)(l + i) = lv;
}

__global__ __launch_bounds__(256) void transpose_bf16(
    const bf16* __restrict__ src, bf16* __restrict__ dst, int R, int C)
{
    __shared__ bf16 tile[32][33];
    const int bx = blockIdx.x * 32;
    const int by = blockIdx.y * 32;
    const int tx = threadIdx.x & 31;
    const int ty = threadIdx.x >> 5;
#pragma unroll
    for (int r = 0; r < 4; r++)
        tile[ty + 8 * r][tx] = src[(size_t)(by + ty + 8 * r) * C + bx + tx];
    __syncthreads();
#pragma unroll
    for (int r = 0; r < 4; r++)
        dst[(size_t)(bx + ty + 8 * r) * R + by + tx] = tile[tx][ty + 8 * r];
}

// ---------------------------------------------------------------------------
// reduce over NS partial slices. MODE 0: sum->bf16. MODE 1: sum+bias->f32.
template<int NS, int MODE>
__global__ __launch_bounds__(256) void reduce_k(
    const float* __restrict__ P, const float* __restrict__ bias,
    float* __restrict__ of, bf16* __restrict__ oh, int n, int Nld)
{
    const int i = (blockIdx.x * 256 + threadIdx.x) * 4;
    if (i >= n) return;
    f32x4 v = *(const f32x4*)(P + i);
#pragma unroll
    for (int s = 1; s < NS; s++)
        v += *(const f32x4*)(P + (size_t)s * n + i);
    if (MODE == 1)
        v += *(const f32x4*)(bias + (i & (Nld - 1)));
    if (MODE == 0) {
        bf16x4 o;
#pragma unroll
        for (int c = 0; c < 4; c++) o[c] = (bf16)v[c];
        *(bf16x4*)(oh + i) = o;
    } else {
        *(f32x4*)(of + i) = v;
    }
}

// ---------------------------------------------------------------------------
// Plain bf16 gemm_bt (32x32x16 core): C[M,N] = A[M,K] B[N,K]^T.
// NSPLIT>0: blockIdx.z = kz -> fp32 partial slice kz.
template<int NSPLIT, int HAS_BIAS, int OUT_BF16>
__global__ __launch_bounds__(256) void gemm_bt(
    const bf16* __restrict__ A, const bf16* __restrict__ B,
    const float* __restrict__ bias,
    float* __restrict__ Cf, bf16* __restrict__ Cb,
    int M, int N, int Ksub, int lda, int ldb)
{
    __shared__ bf16 sA[BM * BK];
    __shared__ bf16 sB[BN * BK];
    const int t    = threadIdx.x;
    const int wave = t >> 6;
    const int lane = t & 63;
    const int l31  = lane & 31;
    const int lhi  = lane >> 5;
    const int wm   = wave >> 1;
    const int wn   = wave & 1;
    const int bm   = blockIdx.y * BM;
    const int bn   = blockIdx.x * BN;
    const int srow = t >> 2;
    const int sseg = t & 3;
    const int kz   = (NSPLIT > 0) ? (int)blockIdx.z : 0;

    A += (size_t)kz * Ksub;
    B += (size_t)kz * Ksub;
    if (NSPLIT > 0) Cf += (size_t)kz * M * N;

    const bf16* ga = A + (size_t)(bm + srow) * lda + sseg * 8;
    const bf16* gb = B + (size_t)(bn + srow) * ldb + sseg * 8;
    char* lA = (char*)sA + wave * 1024;
    char* lB = (char*)sB + wave * 1024;

    f32x16 acc[2][2] = {};

    for (int k0 = 0; k0 < Ksub; k0 += BK) {
        __syncthreads();
        gld_lds16(ga + k0,                      lA);
        gld_lds16(ga + (size_t)64 * lda + k0,   lA + 4096);
        gld_lds16(gb + k0,                      lB);
        gld_lds16(gb + (size_t)64 * ldb + k0,   lB + 4096);
        __syncthreads();
        bf16x8 af[2][2], bfr[2][2];   // [tile][khalf]
#pragma unroll
        for (int mi = 0; mi < 2; mi++)
#pragma unroll
            for (int kh = 0; kh < 2; kh++)
                af[mi][kh] = *(const bf16x8*)
                    &sA[(wm * 64 + mi * 32 + l31) * BK + kh * 16 + lhi * 8];
#pragma unroll
        for (int nj = 0; nj < 2; nj++)
#pragma unroll
            for (int kh = 0; kh < 2; kh++)
                bfr[nj][kh] = *(const bf16x8*)
                    &sB[(wn * 64 + nj * 32 + l31) * BK + kh * 16 + lhi * 8];
#pragma unroll
        for (int kh = 0; kh < 2; kh++)
#pragma unroll
            for (int mi = 0; mi < 2; mi++)
#pragma unroll
                for (int nj = 0; nj < 2; nj++)
                    acc[mi][nj] = __builtin_amdgcn_mfma_f32_32x32x16_bf16(
                        af[mi][kh], bfr[nj][kh], acc[mi][nj], 0, 0, 0);
    }

    // C/D: col = lane&31, row = (reg&3) + 8*(reg>>2) + 4*(lane>>5)  [m74/m101]
#pragma unroll
    for (int mi = 0; mi < 2; mi++)
#pragma unroll
        for (int nj = 0; nj < 2; nj++) {
            const int cg = bn + wn * 64 + nj * 32 + l31;
            const float bv = HAS_BIAS ? bias[cg] : 0.0f;
#pragma unroll
            for (int r = 0; r < 16; r++) {
                const int rg = bm + wm * 64 + mi * 32 + (r & 3) + 8 * (r >> 2) + 4 * lhi;
                const float v = acc[mi][nj][r] + bv;
                const size_t idx = (size_t)rg * N + cg;
                if (NSPLIT > 0)    Cf[idx] = v;
                else if (OUT_BF16) Cb[idx] = (bf16)v;
                else               Cf[idx] = v;
            }
        }
}

// ---------------------------------------------------------------------------
// Split-precision gemm_bt (32x32x16 core, 3 MFMAs: AlBh + AhBl + AhBh).
// BATCH: blockIdx.z picks operand set. NSPLIT>0: split-K fp32 partials.
// NSPLIT==0: HILO? bf16 hi/lo (+bias) : fp32 (+bias if HAS_BIAS).
template<int BATCH, int NSPLIT, int HAS_BIAS, int HILO>
__global__ __launch_bounds__(256) void gemm_bt_split(
    const bf16* __restrict__ Ah0, const bf16* __restrict__ Al0,
    const bf16* __restrict__ Bh0, const bf16* __restrict__ Bl0,
    const float* __restrict__ bias0, bf16* __restrict__ Ch0, bf16* __restrict__ Cl0,
    const bf16* __restrict__ Ah1, const bf16* __restrict__ Al1,
    const bf16* __restrict__ Bh1, const bf16* __restrict__ Bl1,
    const float* __restrict__ bias1, bf16* __restrict__ Ch1, bf16* __restrict__ Cl1,
    float* __restrict__ P, float* __restrict__ Cf,
    int M, int N, int Ksub, int lda, int ldb)
{
    __shared__ bf16 sAh[BM * BK], sAl[BM * BK], sBh[BN * BK], sBl[BN * BK];
    const int t    = threadIdx.x;
    const int wave = t >> 6;
    const int lane = t & 63;
    const int l31  = lane & 31;
    const int lhi  = lane >> 5;
    const int wm   = wave >> 1;
    const int wn   = wave & 1;
    const int bm   = blockIdx.y * BM;
    const int bn   = blockIdx.x * BN;
    const int srow = t >> 2;
    const int sseg = t & 3;

    const int zs = (NSPLIT > 0) ? NSPLIT : 1;
    const int mt = BATCH ? ((int)blockIdx.z / zs) : 0;
    const int kz = (NSPLIT > 0) ? ((int)blockIdx.z % zs) : 0;

    const bf16* Ah = (BATCH && mt) ? Ah1 : Ah0;
    const bf16* Al = (BATCH && mt) ? Al1 : Al0;
    const bf16* Bh = (BATCH && mt) ? Bh1 : Bh0;
    const bf16* Bl = (BATCH && mt) ? Bl1 : Bl0;
    const float* bias = (BATCH && mt) ? bias1 : bias0;
    bf16* Ch = (BATCH && mt) ? Ch1 : Ch0;
    bf16* Cl = (BATCH && mt) ? Cl1 : Cl0;
    if (NSPLIT > 0) P += (size_t)(mt * zs + kz) * M * N;

    const size_t offA = (size_t)(bm + srow) * lda + sseg * 8 + (size_t)kz * Ksub;
    const size_t offB = (size_t)(bn + srow) * ldb + sseg * 8 + (size_t)kz * Ksub;
    char* lAh = (char*)sAh + wave * 1024;
    char* lAl = (char*)sAl + wave * 1024;
    char* lBh = (char*)sBh + wave * 1024;
    char* lBl = (char*)sBl + wave * 1024;

    f32x16 acc[2][2] = {};

    for (int k0 = 0; k0 < Ksub; k0 += BK) {
        __syncthreads();
        gld_lds16(Ah + offA + k0,                    lAh);
        gld_lds16(Ah + offA + (size_t)64 * lda + k0, lAh + 4096);
        gld_lds16(Al + offA + k0,                    lAl);
        gld_lds16(Al + offA + (size_t)64 * lda + k0, lAl + 4096);
        gld_lds16(Bh + offB + k0,                    lBh);
        gld_lds16(Bh + offB + (size_t)64 * ldb + k0, lBh + 4096);
        gld_lds16(Bl + offB + k0,                    lBl);
        gld_lds16(Bl + offB + (size_t)64 * ldb + k0, lBl + 4096);
        __syncthreads();
#pragma unroll
        for (int kh = 0; kh < 2; kh++) {
            bf16x8 ah[2], al[2], bh2[2], bl2[2];
#pragma unroll
            for (int mi = 0; mi < 2; mi++) {
                const int ro = (wm * 64 + mi * 32 + l31) * BK + kh * 16 + lhi * 8;
                ah[mi] = *(const bf16x8*)&sAh[ro];
                al[mi] = *(const bf16x8*)&sAl[ro];
            }
#pragma unroll
            for (int nj = 0; nj < 2; nj++) {
                const int ro = (wn * 64 + nj * 32 + l31) * BK + kh * 16 + lhi * 8;
                bh2[nj] = *(const bf16x8*)&sBh[ro];
                bl2[nj] = *(const bf16x8*)&sBl[ro];
            }
#pragma unroll
            for (int mi = 0; mi < 2; mi++)
#pragma unroll
                for (int nj = 0; nj < 2; nj++) {
                    acc[mi][nj] = __builtin_amdgcn_mfma_f32_32x32x16_bf16(al[mi], bh2[nj], acc[mi][nj], 0, 0, 0);
                    acc[mi][nj] = __builtin_amdgcn_mfma_f32_32x32x16_bf16(ah[mi], bl2[nj], acc[mi][nj], 0, 0, 0);
                    acc[mi][nj] = __builtin_amdgcn_mfma_f32_32x32x16_bf16(ah[mi], bh2[nj], acc[mi][nj], 0, 0, 0);
                }
        }
    }

#pragma unroll
    for (int mi = 0; mi < 2; mi++)
#pragma unroll
        for (int nj = 0; nj < 2; nj++) {
            const int cg = bn + wn * 64 + nj * 32 + l31;
            const float bv = (NSPLIT == 0 && HAS_BIAS) ? bias[cg] : 0.0f;
#pragma unroll
            for (int r = 0; r < 16; r++) {
                const int rg = bm + wm * 64 + mi * 32 + (r & 3) + 8 * (r >> 2) + 4 * lhi;
                const float v = acc[mi][nj][r] + bv;
                const size_t idx = (size_t)rg * N + cg;
                if (NSPLIT > 0) {
                    P[idx] = v;
                } else if (HILO) {
                    const bf16 hh = (bf16)v;
                    Ch[idx] = hh;
                    Cl[idx] = (bf16)(v - (float)hh);
                } else {
                    Cf[idx] = v;
                }
            }
        }
}

// ---------------------------------------------------------------------------
__device__ __forceinline__ float wred_max(float v) {
#pragma unroll
    for (int off = 32; off > 0; off >>= 1) v = fmaxf(v, __shfl_xor(v, off));
    return v;
}
__device__ __forceinline__ float wred_sum(float v) {
#pragma unroll
    for (int off = 32; off > 0; off >>= 1) v += __shfl_xor(v, off);
    return v;
}

__global__ __launch_bounds__(256) void softmax2_kernel(
    float* __restrict__ score, const int* __restrict__ mask,
    const float* __restrict__ wei, bf16* __restrict__ scoreb)
{
    __shared__ float sred[4];
    const int row = blockIdx.x;
    const int t   = threadIdx.x;
    const size_t base = (size_t)row * NKK;
    const int wv = t >> 6, ln = t & 63;

    float l[16], w[16];
    unsigned mb = 0;
#pragma unroll
    for (int s = 0; s < 16; s++) {
        const int j = t + (s << 8);
        l[s] = score[base + j];
        w[s] = wei[base + j];
        if (mask[base + j] != 0) mb |= 1u << s;
    }

    float mx = -__builtin_inff();
#pragma unroll
    for (int s = 0; s < 16; s++) if (mb & (1u << s)) mx = fmaxf(mx, l[s]);
    mx = wred_max(mx);
    if (ln == 0) sred[wv] = mx;
    __syncthreads();
    mx = fmaxf(fmaxf(sred[0], sred[1]), fmaxf(sred[2], sred[3]));
    __syncthreads();
    float sum = 0.f;
#pragma unroll
    for (int s = 0; s < 16; s++) {
        const float e = (mb & (1u << s)) ? __expf(l[s] - mx) : 0.f;
        l[s] = e; sum += e;
    }
    sum = wred_sum(sum);
    if (ln == 0) sred[wv] = sum;
    __syncthreads();
    sum = sred[0] + sred[1] + sred[2] + sred[3];
    __syncthreads();
    const float inv1 = 1.0f / sum;

#pragma unroll
    for (int s = 0; s < 16; s++) l[s] = l[s] * inv1 * w[s];

    float mx2 = -__builtin_inff();
#pragma unroll
    for (int s = 0; s < 16; s++) if (mb & (1u << s)) mx2 = fmaxf(mx2, l[s]);
    mx2 = wred_max(mx2);
    if (ln == 0) sred[wv] = mx2;
    __syncthreads();
    mx2 = fmaxf(fmaxf(sred[0], sred[1]), fmaxf(sred[2], sred[3]));
    __syncthreads();
    float sum2 = 0.f;
#pragma unroll
    for (int s = 0; s < 16; s++) {
        const float e = (mb & (1u << s)) ? __expf(l[s] - mx2) : 0.f;
        l[s] = e; sum2 += e;
    }
    sum2 = wred_sum(sum2);
    if (ln == 0) sred[wv] = sum2;
    __syncthreads();
    sum2 = sred[0] + sred[1] + sred[2] + sred[3];
    const float inv2 = 1.0f / sum2;

#pragma unroll
    for (int s = 0; s < 16; s++) {
        const int j = t + (s << 8);
        const float p = l[s] * inv2;
        score[base + j]  = p;
        scoreb[base + j] = (bf16)p;
    }
}

// ---------------------------------------------------------------------------
extern "C" void kernel_launch(void* const* d_in, const int* in_sizes, int n_in,
                              void* d_out, int out_size, void* d_ws, size_t ws_size,
                              hipStream_t stream)
{
    (void)in_sizes; (void)n_in; (void)out_size;
    const float* q    = (const float*)d_in[0];
    const float* k    = (const float*)d_in[1];
    const int*   mask = (const int*)  d_in[2];
    const float* wei  = (const float*)d_in[3];
    const float* Wq   = (const float*)d_in[4];
    const float* bq   = (const float*)d_in[5];
    const float* Wk   = (const float*)d_in[6];
    const float* bk   = (const float*)d_in[7];
    const float* Wp   = (const float*)d_in[8];
    const float* bp   = (const float*)d_in[9];

    float* out   = (float*)d_out;
    float* score = (float*)d_out + (size_t)NQ * EMB;

    char* ws = (char*)d_ws;
    size_t off = 0;
    auto alloc = [&](size_t bytes) -> char* {
        char* p = ws + off; off += (bytes + 255) & ~(size_t)255; return p;
    };
    const size_t n_qk = (size_t)NQ * EMB;
    const size_t n_w  = (size_t)EMB * EMB;
    const size_t n_sc = (size_t)NQ * NKK;

    bf16* qh   = (bf16*)alloc(n_qk * 2);
    bf16* ql   = (bf16*)alloc(n_qk * 2);
    bf16* kh   = (bf16*)alloc(n_qk * 2);
    bf16* kl   = (bf16*)alloc(n_qk * 2);
    bf16* qxh  = (bf16*)alloc(n_qk * 2);
    bf16* qxl  = (bf16*)alloc(n_qk * 2);
    bf16* kxh  = (bf16*)alloc(n_qk * 2);
    bf16* kxl  = (bf16*)alloc(n_qk * 2);
    bf16* Wqh  = (bf16*)alloc(n_w * 2);
    bf16* Wql  = (bf16*)alloc(n_w * 2);
    bf16* Wkh  = (bf16*)alloc(n_w * 2);
    bf16* Wkl  = (bf16*)alloc(n_w * 2);
    bf16* Wpb  = (bf16*)alloc(n_w * 2);
    bf16* Wpl  = (bf16*)alloc(n_w * 2);   // scratch lo for Wp (unused)
    bf16* kxTb = (bf16*)alloc(n_qk * 2);
    bf16* ctxb = (bf16*)alloc(n_qk * 2);
    bf16* scoreb = (bf16*)alloc(n_sc * 2);
    const size_t base_off = off;
    float* P = (float*)alloc(4 * n_qk * 4);   // 67 MB partials (ctx max)
    const bool ws_ok = (off <= ws_size);
    if (base_off > ws_size) return;

    const int MN = (int)n_qk;

    // 1) prep: q/k hi-lo split (batched), weights (batched)
    prep_pair<<<dim3(n_qk / 1024, 2), 256, 0, stream>>>(q, k, qh, ql, kh, kl, (int)n_qk);
    prep_w3<<<dim3(n_w / 1024, 3), 256, 0, stream>>>(
        Wq, Wk, Wp, Wqh, Wql, Wkh, Wkl, Wpb, Wpl, (int)n_w);

    // 2) projections: batched z=2, no split-K, direct bias + hi/lo epilogue
    gemm_bt_split<1, 0, 1, 1><<<dim3(EMB / BN, NQ / BM, 2), 256, 0, stream>>>(
        qh, ql, Wqh, Wql, bq, qxh, qxl,
        kh, kl, Wkh, Wkl, bk, kxh, kxl,
        nullptr, nullptr, NQ, EMB, EMB, EMB, EMB);

    // 3) kx^T for ctx GEMM B-operand
    transpose_bf16<<<dim3(EMB / 32, NKK / 32), 256, 0, stream>>>(kxh, kxTb, NKK, EMB);

    // 4) score logits = qx kx^T (split precision, fp32 into d_out score region)
    gemm_bt_split<0, 0, 0, 0><<<dim3(NKK / BN, NQ / BM), 256, 0, stream>>>(
        qxh, qxl, kxh, kxl, nullptr, nullptr, nullptr,
        nullptr, nullptr, nullptr, nullptr, nullptr, nullptr, nullptr,
        nullptr, score, NQ, NKK, EMB, EMB, EMB);

    // 5) fused double softmax
    softmax2_kernel<<<dim3(NQ), 256, 0, stream>>>(score, mask, wei, scoreb);

    // 6) ctx = p2 @ kx  (split-K=4)
    if (ws_ok) {
        gemm_bt<4, 0, 0><<<dim3(EMB / BN, NQ / BM, 4), 256, 0, stream>>>(
            scoreb, kxTb, nullptr, P, nullptr, NQ, EMB, NKK / 4, NKK, NKK);
        reduce_k<4, 0><<<dim3(MN / 1024), 256, 0, stream>>>(
            P, nullptr, nullptr, ctxb, MN, EMB);
    } else {
        gemm_bt<0, 0, 1><<<dim3(EMB / BN, NQ / BM), 256, 0, stream>>>(
            scoreb, kxTb, nullptr, nullptr, ctxb, NQ, EMB, NKK, NKK, NKK);
    }

    // 7) out = ctx @ Wp^T + bp  (split-K=2)
    if (ws_ok) {
        gemm_bt<2, 0, 0><<<dim3(EMB / BN, NQ / BM, 2), 256, 0, stream>>>(
            ctxb, Wpb, nullptr, P, nullptr, NQ, EMB, EMB / 2, EMB, EMB);
        reduce_k<2, 1><<<dim3(MN / 1024), 256, 0, stream>>>(
            P, bp, out, nullptr, MN, EMB);
    } else {
        gemm_bt<0, 1, 0><<<dim3(EMB / BN, NQ / BM), 256, 0, stream>>>(
            ctxb, Wpb, bp, out, nullptr, NQ, EMB, EMB, EMB, EMB);
    }
}

// Round 4
// 528.273 us; speedup vs baseline: 1.0502x; 1.0502x over previous
//
#include <hip/hip_runtime.h>

// ---------------------------------------------------------------------------
// Attention_73813307949177
//   kx = k Wk^T + bk ; qx = q Wq^T + bq
//   score = softmax2(softmax1(qx kx^T + bias)*wei + bias)
//   out = (score kx) Wp^T + bp
// Outputs (concat): out [4096,1024] fp32, score [4096,4096] fp32
//
// R3 -> R4:
//  * XOR-swizzled LDS staging (slot r*4 + (s ^ ((r>>1)&3)), 16B granules):
//    global_load_lds fixes slot=lane but the PER-LANE GLOBAL ADDRESS is free,
//    so the swizzle lives in the staging fetch + frag-read addressing.
//    Kills the 16-way bank conflict of the 32x32 frag read (R3: 2.5e7
//    SQ_LDS_BANK_CONFLICT, 143us score GEMM).
//  * ctx split-K 4 -> 2 (halves fp32 partial round-trip).
// 32x32x16 A/B/C-D layouts HW-validated by R3 (absmax unchanged).
// ---------------------------------------------------------------------------

typedef __bf16 bf16;
typedef __bf16 bf16x8 __attribute__((ext_vector_type(8)));
typedef __bf16 bf16x4 __attribute__((ext_vector_type(4)));
typedef float  f32x4  __attribute__((ext_vector_type(4)));
typedef float  f32x16 __attribute__((ext_vector_type(16)));

typedef __attribute__((address_space(1))) void as1_void;
typedef __attribute__((address_space(3))) void as3_void;

#define NQ  4096
#define NKK 4096
#define EMB 1024

#define BM 128
#define BN 128
#define BK 32

__device__ __forceinline__ void gld_lds16(const void* g, void* l) {
    __builtin_amdgcn_global_load_lds((as1_void*)g, (as3_void*)l, 16, 0, 0);
}

// ---------------------------------------------------------------------------
__global__ __launch_bounds__(256) void prep_pair(
    const float* __restrict__ a, const float* __restrict__ b,
    bf16* __restrict__ ah, bf16* __restrict__ al,
    bf16* __restrict__ bh, bf16* __restrict__ bl, int n)
{
    const float* s = blockIdx.y ? b : a;
    bf16* h = blockIdx.y ? bh : ah;
    bf16* l = blockIdx.y ? bl : al;
    const int i = (blockIdx.x * 256 + threadIdx.x) * 4;
    if (i >= n) return;
    f32x4 v = *(const f32x4*)(s + i);
    bf16x4 hv, lv;
#pragma unroll
    for (int c = 0; c < 4; c++) {
        float x = v[c];
        bf16 hh = (bf16)x;
        hv[c] = hh;
        lv[c] = (bf16)(x - (float)hh);
    }
    *(bf16x4*)(h + i) = hv;
    *(bf16x4*)(l + i) = lv;
}

__global__ __launch_bounds__(256) void prep_w3(
    const float* __restrict__ w0, const float* __restrict__ w1, const float* __restrict__ w2,
    bf16* __restrict__ h0, bf16* __restrict__ l0,
    bf16* __restrict__ h1, bf16* __restrict__ l1,
    bf16* __restrict__ h2, bf16* __restrict__ l2, int n)
{
    const int z = blockIdx.y;
    const float* s = (z == 0) ? w0 : (z == 1) ? w1 : w2;
    bf16* h = (z == 0) ? h0 : (z == 1) ? h1 : h2;
    bf16* l = (z == 0) ? l0 : (z == 1) ? l1 : l2;
    const int i = (blockIdx.x * 256 + threadIdx.x) * 4;
    if (i >= n) return;
    f32x4 v = *(const f32x4*)(s + i);
    bf16x4 hv, lv;
#pragma unroll
    for (int c = 0; c < 4; c++) {
        float x = v[c];
        bf16 hh = (bf16)x;
        hv[c] = hh;
        lv[c] = (bf16)(x - (float)hh);
    }
    *(bf16x4*)(h + i) = hv;
    *(bf16x4*)(l + i) = lv;
}

__global__ __launch_bounds__(256) void transpose_bf16(
    const bf16* __restrict__ src, bf16* __restrict__ dst, int R, int C)
{
    __shared__ bf16 tile[32][33];
    const int bx = blockIdx.x * 32;
    const int by = blockIdx.y * 32;
    const int tx = threadIdx.x & 31;
    const int ty = threadIdx.x >> 5;
#pragma unroll
    for (int r = 0; r < 4; r++)
        tile[ty + 8 * r][tx] = src[(size_t)(by + ty + 8 * r) * C + bx + tx];
    __syncthreads();
#pragma unroll
    for (int r = 0; r < 4; r++)
        dst[(size_t)(bx + ty + 8 * r) * R + by + tx] = tile[tx][ty + 8 * r];
}

// ---------------------------------------------------------------------------
template<int NS, int MODE>  // 0: sum->bf16. 1: sum+bias->f32.
__global__ __launch_bounds__(256) void reduce_k(
    const float* __restrict__ P, const float* __restrict__ bias,
    float* __restrict__ of, bf16* __restrict__ oh, int n, int Nld)
{
    const int i = (blockIdx.x * 256 + threadIdx.x) * 4;
    if (i >= n) return;
    f32x4 v = *(const f32x4*)(P + i);
#pragma unroll
    for (int s = 1; s < NS; s++)
        v += *(const f32x4*)(P + (size_t)s * n + i);
    if (MODE == 1)
        v += *(const f32x4*)(bias + (i & (Nld - 1)));
    if (MODE == 0) {
        bf16x4 o;
#pragma unroll
        for (int c = 0; c < 4; c++) o[c] = (bf16)v[c];
        *(bf16x4*)(oh + i) = o;
    } else {
        *(f32x4*)(of + i) = v;
    }
}

// ---------------------------------------------------------------------------
// Plain bf16 gemm_bt (32x32x16 core, swizzled LDS): C = A[M,K] B[N,K]^T.
template<int NSPLIT, int HAS_BIAS, int OUT_BF16>
__global__ __launch_bounds__(256) void gemm_bt(
    const bf16* __restrict__ A, const bf16* __restrict__ B,
    const float* __restrict__ bias,
    float* __restrict__ Cf, bf16* __restrict__ Cb,
    int M, int N, int Ksub, int lda, int ldb)
{
    __shared__ bf16 sA[BM * BK];
    __shared__ bf16 sB[BN * BK];
    const int t    = threadIdx.x;
    const int wave = t >> 6;
    const int lane = t & 63;
    const int l31  = lane & 31;
    const int lhi  = lane >> 5;
    const int wm   = wave >> 1;
    const int wn   = wave & 1;
    const int bm   = blockIdx.y * BM;
    const int bn   = blockIdx.x * BN;
    const int srow = t >> 2;
    const int gseg = (t & 3) ^ ((srow >> 1) & 3);   // staging swizzle
    const int rsw  = (l31 >> 1) & 3;                // frag-read swizzle
    const int kz   = (NSPLIT > 0) ? (int)blockIdx.z : 0;

    A += (size_t)kz * Ksub;
    B += (size_t)kz * Ksub;
    if (NSPLIT > 0) Cf += (size_t)kz * M * N;

    const bf16* ga = A + (size_t)(bm + srow) * lda + gseg * 8;
    const bf16* gb = B + (size_t)(bn + srow) * ldb + gseg * 8;
    char* lA = (char*)sA + wave * 1024;
    char* lB = (char*)sB + wave * 1024;

    f32x16 acc[2][2] = {};

    for (int k0 = 0; k0 < Ksub; k0 += BK) {
        __syncthreads();
        gld_lds16(ga + k0,                      lA);
        gld_lds16(ga + (size_t)64 * lda + k0,   lA + 4096);
        gld_lds16(gb + k0,                      lB);
        gld_lds16(gb + (size_t)64 * ldb + k0,   lB + 4096);
        __syncthreads();
        bf16x8 af[2][2], bfr[2][2];   // [tile][khalf]
#pragma unroll
        for (int mi = 0; mi < 2; mi++)
#pragma unroll
            for (int kh = 0; kh < 2; kh++)
                af[mi][kh] = *(const bf16x8*)
                    &sA[(wm * 64 + mi * 32 + l31) * BK + ((kh * 2 + lhi) ^ rsw) * 8];
#pragma unroll
        for (int nj = 0; nj < 2; nj++)
#pragma unroll
            for (int kh = 0; kh < 2; kh++)
                bfr[nj][kh] = *(const bf16x8*)
                    &sB[(wn * 64 + nj * 32 + l31) * BK + ((kh * 2 + lhi) ^ rsw) * 8];
#pragma unroll
        for (int kh = 0; kh < 2; kh++)
#pragma unroll
            for (int mi = 0; mi < 2; mi++)
#pragma unroll
                for (int nj = 0; nj < 2; nj++)
                    acc[mi][nj] = __builtin_amdgcn_mfma_f32_32x32x16_bf16(
                        af[mi][kh], bfr[nj][kh], acc[mi][nj], 0, 0, 0);
    }

    // C/D: col = lane&31, row = (reg&3) + 8*(reg>>2) + 4*(lane>>5)
#pragma unroll
    for (int mi = 0; mi < 2; mi++)
#pragma unroll
        for (int nj = 0; nj < 2; nj++) {
            const int cg = bn + wn * 64 + nj * 32 + l31;
            const float bv = HAS_BIAS ? bias[cg] : 0.0f;
#pragma unroll
            for (int r = 0; r < 16; r++) {
                const int rg = bm + wm * 64 + mi * 32 + (r & 3) + 8 * (r >> 2) + 4 * lhi;
                const float v = acc[mi][nj][r] + bv;
                const size_t idx = (size_t)rg * N + cg;
                if (NSPLIT > 0)    Cf[idx] = v;
                else if (OUT_BF16) Cb[idx] = (bf16)v;
                else               Cf[idx] = v;
            }
        }
}

// ---------------------------------------------------------------------------
// Split-precision gemm_bt (32x32x16 core, swizzled LDS; AlBh + AhBl + AhBh).
template<int BATCH, int NSPLIT, int HAS_BIAS, int HILO>
__global__ __launch_bounds__(256) void gemm_bt_split(
    const bf16* __restrict__ Ah0, const bf16* __restrict__ Al0,
    const bf16* __restrict__ Bh0, const bf16* __restrict__ Bl0,
    const float* __restrict__ bias0, bf16* __restrict__ Ch0, bf16* __restrict__ Cl0,
    const bf16* __restrict__ Ah1, const bf16* __restrict__ Al1,
    const bf16* __restrict__ Bh1, const bf16* __restrict__ Bl1,
    const float* __restrict__ bias1, bf16* __restrict__ Ch1, bf16* __restrict__ Cl1,
    float* __restrict__ P, float* __restrict__ Cf,
    int M, int N, int Ksub, int lda, int ldb)
{
    __shared__ bf16 sAh[BM * BK], sAl[BM * BK], sBh[BN * BK], sBl[BN * BK];
    const int t    = threadIdx.x;
    const int wave = t >> 6;
    const int lane = t & 63;
    const int l31  = lane & 31;
    const int lhi  = lane >> 5;
    const int wm   = wave >> 1;
    const int wn   = wave & 1;
    const int bm   = blockIdx.y * BM;
    const int bn   = blockIdx.x * BN;
    const int srow = t >> 2;
    const int gseg = (t & 3) ^ ((srow >> 1) & 3);
    const int rsw  = (l31 >> 1) & 3;

    const int zs = (NSPLIT > 0) ? NSPLIT : 1;
    const int mt = BATCH ? ((int)blockIdx.z / zs) : 0;
    const int kz = (NSPLIT > 0) ? ((int)blockIdx.z % zs) : 0;

    const bf16* Ah = (BATCH && mt) ? Ah1 : Ah0;
    const bf16* Al = (BATCH && mt) ? Al1 : Al0;
    const bf16* Bh = (BATCH && mt) ? Bh1 : Bh0;
    const bf16* Bl = (BATCH && mt) ? Bl1 : Bl0;
    const float* bias = (BATCH && mt) ? bias1 : bias0;
    bf16* Ch = (BATCH && mt) ? Ch1 : Ch0;
    bf16* Cl = (BATCH && mt) ? Cl1 : Cl0;
    if (NSPLIT > 0) P += (size_t)(mt * zs + kz) * M * N;

    const size_t offA = (size_t)(bm + srow) * lda + gseg * 8 + (size_t)kz * Ksub;
    const size_t offB = (size_t)(bn + srow) * ldb + gseg * 8 + (size_t)kz * Ksub;
    char* lAh = (char*)sAh + wave * 1024;
    char* lAl = (char*)sAl + wave * 1024;
    char* lBh = (char*)sBh + wave * 1024;
    char* lBl = (char*)sBl + wave * 1024;

    f32x16 acc[2][2] = {};

    for (int k0 = 0; k0 < Ksub; k0 += BK) {
        __syncthreads();
        gld_lds16(Ah + offA + k0,                    lAh);
        gld_lds16(Ah + offA + (size_t)64 * lda + k0, lAh + 4096);
        gld_lds16(Al + offA + k0,                    lAl);
        gld_lds16(Al + offA + (size_t)64 * lda + k0, lAl + 4096);
        gld_lds16(Bh + offB + k0,                    lBh);
        gld_lds16(Bh + offB + (size_t)64 * ldb + k0, lBh + 4096);
        gld_lds16(Bl + offB + k0,                    lBl);
        gld_lds16(Bl + offB + (size_t)64 * ldb + k0, lBl + 4096);
        __syncthreads();
#pragma unroll
        for (int kh = 0; kh < 2; kh++) {
            const int ksw = ((kh * 2 + lhi) ^ rsw) * 8;
            bf16x8 ah[2], al[2], bh2[2], bl2[2];
#pragma unroll
            for (int mi = 0; mi < 2; mi++) {
                const int ro = (wm * 64 + mi * 32 + l31) * BK + ksw;
                ah[mi] = *(const bf16x8*)&sAh[ro];
                al[mi] = *(const bf16x8*)&sAl[ro];
            }
#pragma unroll
            for (int nj = 0; nj < 2; nj++) {
                const int ro = (wn * 64 + nj * 32 + l31) * BK + ksw;
                bh2[nj] = *(const bf16x8*)&sBh[ro];
                bl2[nj] = *(const bf16x8*)&sBl[ro];
            }
#pragma unroll
            for (int mi = 0; mi < 2; mi++)
#pragma unroll
                for (int nj = 0; nj < 2; nj++) {
                    acc[mi][nj] = __builtin_amdgcn_mfma_f32_32x32x16_bf16(al[mi], bh2[nj], acc[mi][nj], 0, 0, 0);
                    acc[mi][nj] = __builtin_amdgcn_mfma_f32_32x32x16_bf16(ah[mi], bl2[nj], acc[mi][nj], 0, 0, 0);
                    acc[mi][nj] = __builtin_amdgcn_mfma_f32_32x32x16_bf16(ah[mi], bh2[nj], acc[mi][nj], 0, 0, 0);
                }
        }
    }

#pragma unroll
    for (int mi = 0; mi < 2; mi++)
#pragma unroll
        for (int nj = 0; nj < 2; nj++) {
            const int cg = bn + wn * 64 + nj * 32 + l31;
            const float bv = (NSPLIT == 0 && HAS_BIAS) ? bias[cg] : 0.0f;
#pragma unroll
            for (int r = 0; r < 16; r++) {
                const int rg = bm + wm * 64 + mi * 32 + (r & 3) + 8 * (r >> 2) + 4 * lhi;
                const float v = acc[mi][nj][r] + bv;
                const size_t idx = (size_t)rg * N + cg;
                if (NSPLIT > 0) {
                    P[idx] = v;
                } else if (HILO) {
                    const bf16 hh = (bf16)v;
                    Ch[idx] = hh;
                    Cl[idx] = (bf16)(v - (float)hh);
                } else {
                    Cf[idx] = v;
                }
            }
        }
}

// ---------------------------------------------------------------------------
__device__ __forceinline__ float wred_max(float v) {
#pragma unroll
    for (int off = 32; off > 0; off >>= 1) v = fmaxf(v, __shfl_xor(v, off));
    return v;
}
__device__ __forceinline__ float wred_sum(float v) {
#pragma unroll
    for (int off = 32; off > 0; off >>= 1) v += __shfl_xor(v, off);
    return v;
}

__global__ __launch_bounds__(256) void softmax2_kernel(
    float* __restrict__ score, const int* __restrict__ mask,
    const float* __restrict__ wei, bf16* __restrict__ scoreb)
{
    __shared__ float sred[4];
    const int row = blockIdx.x;
    const int t   = threadIdx.x;
    const size_t base = (size_t)row * NKK;
    const int wv = t >> 6, ln = t & 63;

    float l[16], w[16];
    unsigned mb = 0;
#pragma unroll
    for (int s = 0; s < 16; s++) {
        const int j = t + (s << 8);
        l[s] = score[base + j];
        w[s] = wei[base + j];
        if (mask[base + j] != 0) mb |= 1u << s;
    }

    float mx = -__builtin_inff();
#pragma unroll
    for (int s = 0; s < 16; s++) if (mb & (1u << s)) mx = fmaxf(mx, l[s]);
    mx = wred_max(mx);
    if (ln == 0) sred[wv] = mx;
    __syncthreads();
    mx = fmaxf(fmaxf(sred[0], sred[1]), fmaxf(sred[2], sred[3]));
    __syncthreads();
    float sum = 0.f;
#pragma unroll
    for (int s = 0; s < 16; s++) {
        const float e = (mb & (1u << s)) ? __expf(l[s] - mx) : 0.f;
        l[s] = e; sum += e;
    }
    sum = wred_sum(sum);
    if (ln == 0) sred[wv] = sum;
    __syncthreads();
    sum = sred[0] + sred[1] + sred[2] + sred[3];
    __syncthreads();
    const float inv1 = 1.0f / sum;

#pragma unroll
    for (int s = 0; s < 16; s++) l[s] = l[s] * inv1 * w[s];

    float mx2 = -__builtin_inff();
#pragma unroll
    for (int s = 0; s < 16; s++) if (mb & (1u << s)) mx2 = fmaxf(mx2, l[s]);
    mx2 = wred_max(mx2);
    if (ln == 0) sred[wv] = mx2;
    __syncthreads();
    mx2 = fmaxf(fmaxf(sred[0], sred[1]), fmaxf(sred[2], sred[3]));
    __syncthreads();
    float sum2 = 0.f;
#pragma unroll
    for (int s = 0; s < 16; s++) {
        const float e = (mb & (1u << s)) ? __expf(l[s] - mx2) : 0.f;
        l[s] = e; sum2 += e;
    }
    sum2 = wred_sum(sum2);
    if (ln == 0) sred[wv] = sum2;
    __syncthreads();
    sum2 = sred[0] + sred[1] + sred[2] + sred[3];
    const float inv2 = 1.0f / sum2;

#pragma unroll
    for (int s = 0; s < 16; s++) {
        const int j = t + (s << 8);
        const float p = l[s] * inv2;
        score[base + j]  = p;
        scoreb[base + j] = (bf16)p;
    }
}

// ---------------------------------------------------------------------------
extern "C" void kernel_launch(void* const* d_in, const int* in_sizes, int n_in,
                              void* d_out, int out_size, void* d_ws, size_t ws_size,
                              hipStream_t stream)
{
    (void)in_sizes; (void)n_in; (void)out_size;
    const float* q    = (const float*)d_in[0];
    const float* k    = (const float*)d_in[1];
    const int*   mask = (const int*)  d_in[2];
    const float* wei  = (const float*)d_in[3];
    const float* Wq   = (const float*)d_in[4];
    const float* bq   = (const float*)d_in[5];
    const float* Wk   = (const float*)d_in[6];
    const float* bk   = (const float*)d_in[7];
    const float* Wp   = (const float*)d_in[8];
    const float* bp   = (const float*)d_in[9];

    float* out   = (float*)d_out;
    float* score = (float*)d_out + (size_t)NQ * EMB;

    char* ws = (char*)d_ws;
    size_t off = 0;
    auto alloc = [&](size_t bytes) -> char* {
        char* p = ws + off; off += (bytes + 255) & ~(size_t)255; return p;
    };
    const size_t n_qk = (size_t)NQ * EMB;
    const size_t n_w  = (size_t)EMB * EMB;
    const size_t n_sc = (size_t)NQ * NKK;

    bf16* qh   = (bf16*)alloc(n_qk * 2);
    bf16* ql   = (bf16*)alloc(n_qk * 2);
    bf16* kh   = (bf16*)alloc(n_qk * 2);
    bf16* kl   = (bf16*)alloc(n_qk * 2);
    bf16* qxh  = (bf16*)alloc(n_qk * 2);
    bf16* qxl  = (bf16*)alloc(n_qk * 2);
    bf16* kxh  = (bf16*)alloc(n_qk * 2);
    bf16* kxl  = (bf16*)alloc(n_qk * 2);
    bf16* Wqh  = (bf16*)alloc(n_w * 2);
    bf16* Wql  = (bf16*)alloc(n_w * 2);
    bf16* Wkh  = (bf16*)alloc(n_w * 2);
    bf16* Wkl  = (bf16*)alloc(n_w * 2);
    bf16* Wpb  = (bf16*)alloc(n_w * 2);
    bf16* Wpl  = (bf16*)alloc(n_w * 2);
    bf16* kxTb = (bf16*)alloc(n_qk * 2);
    bf16* ctxb = (bf16*)alloc(n_qk * 2);
    bf16* scoreb = (bf16*)alloc(n_sc * 2);
    const size_t base_off = off;
    float* P = (float*)alloc(2 * n_qk * 4);   // 33.5 MB partials (split-K=2)
    const bool ws_ok = (off <= ws_size);
    if (base_off > ws_size) return;

    const int MN = (int)n_qk;

    // 1) prep
    prep_pair<<<dim3(n_qk / 1024, 2), 256, 0, stream>>>(q, k, qh, ql, kh, kl, (int)n_qk);
    prep_w3<<<dim3(n_w / 1024, 3), 256, 0, stream>>>(
        Wq, Wk, Wp, Wqh, Wql, Wkh, Wkl, Wpb, Wpl, (int)n_w);

    // 2) projections: batched z=2, direct bias + hi/lo epilogue
    gemm_bt_split<1, 0, 1, 1><<<dim3(EMB / BN, NQ / BM, 2), 256, 0, stream>>>(
        qh, ql, Wqh, Wql, bq, qxh, qxl,
        kh, kl, Wkh, Wkl, bk, kxh, kxl,
        nullptr, nullptr, NQ, EMB, EMB, EMB, EMB);

    // 3) kx^T for ctx GEMM B-operand
    transpose_bf16<<<dim3(EMB / 32, NKK / 32), 256, 0, stream>>>(kxh, kxTb, NKK, EMB);

    // 4) score logits = qx kx^T (split precision, fp32 into d_out score region)
    gemm_bt_split<0, 0, 0, 0><<<dim3(NKK / BN, NQ / BM), 256, 0, stream>>>(
        qxh, qxl, kxh, kxl, nullptr, nullptr, nullptr,
        nullptr, nullptr, nullptr, nullptr, nullptr, nullptr, nullptr,
        nullptr, score, NQ, NKK, EMB, EMB, EMB);

    // 5) fused double softmax
    softmax2_kernel<<<dim3(NQ), 256, 0, stream>>>(score, mask, wei, scoreb);

    // 6) ctx = p2 @ kx  (split-K=2)
    if (ws_ok) {
        gemm_bt<2, 0, 0><<<dim3(EMB / BN, NQ / BM, 2), 256, 0, stream>>>(
            scoreb, kxTb, nullptr, P, nullptr, NQ, EMB, NKK / 2, NKK, NKK);
        reduce_k<2, 0><<<dim3(MN / 1024), 256, 0, stream>>>(
            P, nullptr, nullptr, ctxb, MN, EMB);
    } else {
        gemm_bt<0, 0, 1><<<dim3(EMB / BN, NQ / BM), 256, 0, stream>>>(
            scoreb, kxTb, nullptr, nullptr, ctxb, NQ, EMB, NKK, NKK, NKK);
    }

    // 7) out = ctx @ Wp^T + bp  (split-K=2)
    if (ws_ok) {
        gemm_bt<2, 0, 0><<<dim3(EMB / BN, NQ / BM, 2), 256, 0, stream>>>(
            ctxb, Wpb, nullptr, P, nullptr, NQ, EMB, EMB / 2, EMB, EMB);
        reduce_k<2, 1><<<dim3(MN / 1024), 256, 0, stream>>>(
            P, bp, out, nullptr, MN, EMB);
    } else {
        gemm_bt<0, 1, 0><<<dim3(EMB / BN, NQ / BM), 256, 0, stream>>>(
            ctxb, Wpb, bp, out, nullptr, NQ, EMB, EMB, EMB, EMB);
    }
}

// Round 5
// 503.851 us; speedup vs baseline: 1.1011x; 1.0485x over previous
//
#include <hip/hip_runtime.h>

// ---------------------------------------------------------------------------
// Attention_73813307949177
//   kx = k Wk^T + bk ; qx = q Wq^T + bq
//   score = softmax2(softmax1(qx kx^T + bias)*wei + bias)
//   out = (score kx) Wp^T + bp
// Outputs (concat): out [4096,1024] fp32, score [4096,4096] fp32
//
// R4 -> R5: score GEMM is LDS-read-BW bound (model: 35% MfmaUtil == measured).
// New gemm_score: 4x2 wave tile (wave 128x64), block 128x256, reads/MFMA
// 0.667 -> 0.5, MFMA:LDS cycle ratio ~2.7x better. launch_bounds(256,2).
// ---------------------------------------------------------------------------

typedef __bf16 bf16;
typedef __bf16 bf16x8 __attribute__((ext_vector_type(8)));
typedef __bf16 bf16x4 __attribute__((ext_vector_type(4)));
typedef float  f32x4  __attribute__((ext_vector_type(4)));
typedef float  f32x16 __attribute__((ext_vector_type(16)));

typedef __attribute__((address_space(1))) void as1_void;
typedef __attribute__((address_space(3))) void as3_void;

#define NQ  4096
#define NKK 4096
#define EMB 1024

#define BM 128
#define BN 128
#define BK 32

__device__ __forceinline__ void gld_lds16(const void* g, void* l) {
    __builtin_amdgcn_global_load_lds((as1_void*)g, (as3_void*)l, 16, 0, 0);
}

// ---------------------------------------------------------------------------
__global__ __launch_bounds__(256) void prep_pair(
    const float* __restrict__ a, const float* __restrict__ b,
    bf16* __restrict__ ah, bf16* __restrict__ al,
    bf16* __restrict__ bh, bf16* __restrict__ bl, int n)
{
    const float* s = blockIdx.y ? b : a;
    bf16* h = blockIdx.y ? bh : ah;
    bf16* l = blockIdx.y ? bl : al;
    const int i = (blockIdx.x * 256 + threadIdx.x) * 4;
    if (i >= n) return;
    f32x4 v = *(const f32x4*)(s + i);
    bf16x4 hv, lv;
#pragma unroll
    for (int c = 0; c < 4; c++) {
        float x = v[c];
        bf16 hh = (bf16)x;
        hv[c] = hh;
        lv[c] = (bf16)(x - (float)hh);
    }
    *(bf16x4*)(h + i) = hv;
    *(bf16x4*)(l + i) = lv;
}

__global__ __launch_bounds__(256) void prep_w3(
    const float* __restrict__ w0, const float* __restrict__ w1, const float* __restrict__ w2,
    bf16* __restrict__ h0, bf16* __restrict__ l0,
    bf16* __restrict__ h1, bf16* __restrict__ l1,
    bf16* __restrict__ h2, bf16* __restrict__ l2, int n)
{
    const int z = blockIdx.y;
    const float* s = (z == 0) ? w0 : (z == 1) ? w1 : w2;
    bf16* h = (z == 0) ? h0 : (z == 1) ? h1 : h2;
    bf16* l = (z == 0) ? l0 : (z == 1) ? l1 : l2;
    const int i = (blockIdx.x * 256 + threadIdx.x) * 4;
    if (i >= n) return;
    f32x4 v = *(const f32x4*)(s + i);
    bf16x4 hv, lv;
#pragma unroll
    for (int c = 0; c < 4; c++) {
        float x = v[c];
        bf16 hh = (bf16)x;
        hv[c] = hh;
        lv[c] = (bf16)(x - (float)hh);
    }
    *(bf16x4*)(h + i) = hv;
    *(bf16x4*)(l + i) = lv;
}

__global__ __launch_bounds__(256) void transpose_bf16(
    const bf16* __restrict__ src, bf16* __restrict__ dst, int R, int C)
{
    __shared__ bf16 tile[32][33];
    const int bx = blockIdx.x * 32;
    const int by = blockIdx.y * 32;
    const int tx = threadIdx.x & 31;
    const int ty = threadIdx.x >> 5;
#pragma unroll
    for (int r = 0; r < 4; r++)
        tile[ty + 8 * r][tx] = src[(size_t)(by + ty + 8 * r) * C + bx + tx];
    __syncthreads();
#pragma unroll
    for (int r = 0; r < 4; r++)
        dst[(size_t)(bx + ty + 8 * r) * R + by + tx] = tile[tx][ty + 8 * r];
}

// ---------------------------------------------------------------------------
template<int NS, int MODE>  // 0: sum->bf16. 1: sum+bias->f32.
__global__ __launch_bounds__(256) void reduce_k(
    const float* __restrict__ P, const float* __restrict__ bias,
    float* __restrict__ of, bf16* __restrict__ oh, int n, int Nld)
{
    const int i = (blockIdx.x * 256 + threadIdx.x) * 4;
    if (i >= n) return;
    f32x4 v = *(const f32x4*)(P + i);
#pragma unroll
    for (int s = 1; s < NS; s++)
        v += *(const f32x4*)(P + (size_t)s * n + i);
    if (MODE == 1)
        v += *(const f32x4*)(bias + (i & (Nld - 1)));
    if (MODE == 0) {
        bf16x4 o;
#pragma unroll
        for (int c = 0; c < 4; c++) o[c] = (bf16)v[c];
        *(bf16x4*)(oh + i) = o;
    } else {
        *(f32x4*)(of + i) = v;
    }
}

// ---------------------------------------------------------------------------
// Plain bf16 gemm_bt (32x32x16 core, swizzled LDS): C = A[M,K] B[N,K]^T.
template<int NSPLIT, int HAS_BIAS, int OUT_BF16>
__global__ __launch_bounds__(256) void gemm_bt(
    const bf16* __restrict__ A, const bf16* __restrict__ B,
    const float* __restrict__ bias,
    float* __restrict__ Cf, bf16* __restrict__ Cb,
    int M, int N, int Ksub, int lda, int ldb)
{
    __shared__ bf16 sA[BM * BK];
    __shared__ bf16 sB[BN * BK];
    const int t    = threadIdx.x;
    const int wave = t >> 6;
    const int lane = t & 63;
    const int l31  = lane & 31;
    const int lhi  = lane >> 5;
    const int wm   = wave >> 1;
    const int wn   = wave & 1;
    const int bm   = blockIdx.y * BM;
    const int bn   = blockIdx.x * BN;
    const int srow = t >> 2;
    const int gseg = (t & 3) ^ ((srow >> 1) & 3);
    const int rsw  = (l31 >> 1) & 3;
    const int kz   = (NSPLIT > 0) ? (int)blockIdx.z : 0;

    A += (size_t)kz * Ksub;
    B += (size_t)kz * Ksub;
    if (NSPLIT > 0) Cf += (size_t)kz * M * N;

    const bf16* ga = A + (size_t)(bm + srow) * lda + gseg * 8;
    const bf16* gb = B + (size_t)(bn + srow) * ldb + gseg * 8;
    char* lA = (char*)sA + wave * 1024;
    char* lB = (char*)sB + wave * 1024;

    f32x16 acc[2][2] = {};

    for (int k0 = 0; k0 < Ksub; k0 += BK) {
        __syncthreads();
        gld_lds16(ga + k0,                      lA);
        gld_lds16(ga + (size_t)64 * lda + k0,   lA + 4096);
        gld_lds16(gb + k0,                      lB);
        gld_lds16(gb + (size_t)64 * ldb + k0,   lB + 4096);
        __syncthreads();
        bf16x8 af[2][2], bfr[2][2];
#pragma unroll
        for (int mi = 0; mi < 2; mi++)
#pragma unroll
            for (int kh = 0; kh < 2; kh++)
                af[mi][kh] = *(const bf16x8*)
                    &sA[(wm * 64 + mi * 32 + l31) * BK + ((kh * 2 + lhi) ^ rsw) * 8];
#pragma unroll
        for (int nj = 0; nj < 2; nj++)
#pragma unroll
            for (int kh = 0; kh < 2; kh++)
                bfr[nj][kh] = *(const bf16x8*)
                    &sB[(wn * 64 + nj * 32 + l31) * BK + ((kh * 2 + lhi) ^ rsw) * 8];
#pragma unroll
        for (int kh = 0; kh < 2; kh++)
#pragma unroll
            for (int mi = 0; mi < 2; mi++)
#pragma unroll
                for (int nj = 0; nj < 2; nj++)
                    acc[mi][nj] = __builtin_amdgcn_mfma_f32_32x32x16_bf16(
                        af[mi][kh], bfr[nj][kh], acc[mi][nj], 0, 0, 0);
    }

#pragma unroll
    for (int mi = 0; mi < 2; mi++)
#pragma unroll
        for (int nj = 0; nj < 2; nj++) {
            const int cg = bn + wn * 64 + nj * 32 + l31;
            const float bv = HAS_BIAS ? bias[cg] : 0.0f;
#pragma unroll
            for (int r = 0; r < 16; r++) {
                const int rg = bm + wm * 64 + mi * 32 + (r & 3) + 8 * (r >> 2) + 4 * lhi;
                const float v = acc[mi][nj][r] + bv;
                const size_t idx = (size_t)rg * N + cg;
                if (NSPLIT > 0)    Cf[idx] = v;
                else if (OUT_BF16) Cb[idx] = (bf16)v;
                else               Cf[idx] = v;
            }
        }
}

// ---------------------------------------------------------------------------
// Split-precision gemm_bt (32x32x16, 2x2 wave tile) — used for projections.
template<int BATCH, int HAS_BIAS, int HILO>
__global__ __launch_bounds__(256) void gemm_bt_split(
    const bf16* __restrict__ Ah0, const bf16* __restrict__ Al0,
    const bf16* __restrict__ Bh0, const bf16* __restrict__ Bl0,
    const float* __restrict__ bias0, bf16* __restrict__ Ch0, bf16* __restrict__ Cl0,
    const bf16* __restrict__ Ah1, const bf16* __restrict__ Al1,
    const bf16* __restrict__ Bh1, const bf16* __restrict__ Bl1,
    const float* __restrict__ bias1, bf16* __restrict__ Ch1, bf16* __restrict__ Cl1,
    float* __restrict__ Cf,
    int M, int N, int K)
{
    __shared__ bf16 sAh[BM * BK], sAl[BM * BK], sBh[BN * BK], sBl[BN * BK];
    const int t    = threadIdx.x;
    const int wave = t >> 6;
    const int lane = t & 63;
    const int l31  = lane & 31;
    const int lhi  = lane >> 5;
    const int wm   = wave >> 1;
    const int wn   = wave & 1;
    const int bm   = blockIdx.y * BM;
    const int bn   = blockIdx.x * BN;
    const int srow = t >> 2;
    const int gseg = (t & 3) ^ ((srow >> 1) & 3);
    const int rsw  = (l31 >> 1) & 3;

    const int mt = BATCH ? (int)blockIdx.z : 0;

    const bf16* Ah = (BATCH && mt) ? Ah1 : Ah0;
    const bf16* Al = (BATCH && mt) ? Al1 : Al0;
    const bf16* Bh = (BATCH && mt) ? Bh1 : Bh0;
    const bf16* Bl = (BATCH && mt) ? Bl1 : Bl0;
    const float* bias = (BATCH && mt) ? bias1 : bias0;
    bf16* Ch = (BATCH && mt) ? Ch1 : Ch0;
    bf16* Cl = (BATCH && mt) ? Cl1 : Cl0;

    const size_t offA = (size_t)(bm + srow) * K + gseg * 8;
    const size_t offB = (size_t)(bn + srow) * K + gseg * 8;
    char* lAh = (char*)sAh + wave * 1024;
    char* lAl = (char*)sAl + wave * 1024;
    char* lBh = (char*)sBh + wave * 1024;
    char* lBl = (char*)sBl + wave * 1024;

    f32x16 acc[2][2] = {};

    for (int k0 = 0; k0 < K; k0 += BK) {
        __syncthreads();
        gld_lds16(Ah + offA + k0,                  lAh);
        gld_lds16(Ah + offA + (size_t)64 * K + k0, lAh + 4096);
        gld_lds16(Al + offA + k0,                  lAl);
        gld_lds16(Al + offA + (size_t)64 * K + k0, lAl + 4096);
        gld_lds16(Bh + offB + k0,                  lBh);
        gld_lds16(Bh + offB + (size_t)64 * K + k0, lBh + 4096);
        gld_lds16(Bl + offB + k0,                  lBl);
        gld_lds16(Bl + offB + (size_t)64 * K + k0, lBl + 4096);
        __syncthreads();
#pragma unroll
        for (int kh = 0; kh < 2; kh++) {
            const int ksw = ((kh * 2 + lhi) ^ rsw) * 8;
            bf16x8 ah[2], al[2], bh2[2], bl2[2];
#pragma unroll
            for (int mi = 0; mi < 2; mi++) {
                const int ro = (wm * 64 + mi * 32 + l31) * BK + ksw;
                ah[mi] = *(const bf16x8*)&sAh[ro];
                al[mi] = *(const bf16x8*)&sAl[ro];
            }
#pragma unroll
            for (int nj = 0; nj < 2; nj++) {
                const int ro = (wn * 64 + nj * 32 + l31) * BK + ksw;
                bh2[nj] = *(const bf16x8*)&sBh[ro];
                bl2[nj] = *(const bf16x8*)&sBl[ro];
            }
#pragma unroll
            for (int mi = 0; mi < 2; mi++)
#pragma unroll
                for (int nj = 0; nj < 2; nj++) {
                    acc[mi][nj] = __builtin_amdgcn_mfma_f32_32x32x16_bf16(al[mi], bh2[nj], acc[mi][nj], 0, 0, 0);
                    acc[mi][nj] = __builtin_amdgcn_mfma_f32_32x32x16_bf16(ah[mi], bl2[nj], acc[mi][nj], 0, 0, 0);
                    acc[mi][nj] = __builtin_amdgcn_mfma_f32_32x32x16_bf16(ah[mi], bh2[nj], acc[mi][nj], 0, 0, 0);
                }
        }
    }

#pragma unroll
    for (int mi = 0; mi < 2; mi++)
#pragma unroll
        for (int nj = 0; nj < 2; nj++) {
            const int cg = bn + wn * 64 + nj * 32 + l31;
            const float bv = HAS_BIAS ? bias[cg] : 0.0f;
#pragma unroll
            for (int r = 0; r < 16; r++) {
                const int rg = bm + wm * 64 + mi * 32 + (r & 3) + 8 * (r >> 2) + 4 * lhi;
                const float v = acc[mi][nj][r] + bv;
                const size_t idx = (size_t)rg * N + cg;
                if (HILO) {
                    const bf16 hh = (bf16)v;
                    Ch[idx] = hh;
                    Cl[idx] = (bf16)(v - (float)hh);
                } else {
                    Cf[idx] = v;
                }
            }
        }
}

// ---------------------------------------------------------------------------
// Score GEMM: split precision, 4x2 wave tile (wave = 128x64), block 128x256.
// 48 KB LDS, 512 blocks at NQ=NKK=4096. LDS-BW-optimized: 0.5 reads/MFMA.
__global__ __launch_bounds__(256, 2) void gemm_score(
    const bf16* __restrict__ Ah, const bf16* __restrict__ Al,
    const bf16* __restrict__ Bh, const bf16* __restrict__ Bl,
    float* __restrict__ Cf, int N, int K)
{
    __shared__ bf16 sAh[128 * BK], sAl[128 * BK], sBh[256 * BK], sBl[256 * BK];
    const int t    = threadIdx.x;
    const int wave = t >> 6;
    const int lane = t & 63;
    const int l31  = lane & 31;
    const int lhi  = lane >> 5;
    const int bm   = blockIdx.y * 128;
    const int bn   = blockIdx.x * 256;
    const int srow = t >> 2;
    const int gseg = (t & 3) ^ ((srow >> 1) & 3);
    const int rsw  = (l31 >> 1) & 3;

    const size_t offA = (size_t)(bm + srow) * K + gseg * 8;
    const size_t offB = (size_t)(bn + srow) * K + gseg * 8;
    char* lAh = (char*)sAh + wave * 1024;
    char* lAl = (char*)sAl + wave * 1024;
    char* lBh = (char*)sBh + wave * 1024;
    char* lBl = (char*)sBl + wave * 1024;

    f32x16 acc[4][2] = {};

    for (int k0 = 0; k0 < K; k0 += BK) {
        __syncthreads();
        gld_lds16(Ah + offA + k0,                  lAh);
        gld_lds16(Ah + offA + (size_t)64 * K + k0, lAh + 4096);
        gld_lds16(Al + offA + k0,                  lAl);
        gld_lds16(Al + offA + (size_t)64 * K + k0, lAl + 4096);
#pragma unroll
        for (int rb = 0; rb < 4; rb++) {
            gld_lds16(Bh + offB + (size_t)(64 * rb) * K + k0, lBh + rb * 4096);
            gld_lds16(Bl + offB + (size_t)(64 * rb) * K + k0, lBl + rb * 4096);
        }
        __syncthreads();
#pragma unroll
        for (int kh = 0; kh < 2; kh++) {
            const int ksw = ((kh * 2 + lhi) ^ rsw) * 8;
            bf16x8 ah[4], al[4], bh2[2], bl2[2];
#pragma unroll
            for (int mi = 0; mi < 4; mi++) {
                const int ro = (mi * 32 + l31) * BK + ksw;
                ah[mi] = *(const bf16x8*)&sAh[ro];
                al[mi] = *(const bf16x8*)&sAl[ro];
            }
#pragma unroll
            for (int nj = 0; nj < 2; nj++) {
                const int ro = (wave * 64 + nj * 32 + l31) * BK + ksw;
                bh2[nj] = *(const bf16x8*)&sBh[ro];
                bl2[nj] = *(const bf16x8*)&sBl[ro];
            }
#pragma unroll
            for (int mi = 0; mi < 4; mi++)
#pragma unroll
                for (int nj = 0; nj < 2; nj++) {
                    acc[mi][nj] = __builtin_amdgcn_mfma_f32_32x32x16_bf16(al[mi], bh2[nj], acc[mi][nj], 0, 0, 0);
                    acc[mi][nj] = __builtin_amdgcn_mfma_f32_32x32x16_bf16(ah[mi], bl2[nj], acc[mi][nj], 0, 0, 0);
                    acc[mi][nj] = __builtin_amdgcn_mfma_f32_32x32x16_bf16(ah[mi], bh2[nj], acc[mi][nj], 0, 0, 0);
                }
        }
    }

#pragma unroll
    for (int mi = 0; mi < 4; mi++)
#pragma unroll
        for (int nj = 0; nj < 2; nj++) {
            const int cg = bn + wave * 64 + nj * 32 + l31;
#pragma unroll
            for (int r = 0; r < 16; r++) {
                const int rg = bm + mi * 32 + (r & 3) + 8 * (r >> 2) + 4 * lhi;
                Cf[(size_t)rg * N + cg] = acc[mi][nj][r];
            }
        }
}

// ---------------------------------------------------------------------------
__device__ __forceinline__ float wred_max(float v) {
#pragma unroll
    for (int off = 32; off > 0; off >>= 1) v = fmaxf(v, __shfl_xor(v, off));
    return v;
}
__device__ __forceinline__ float wred_sum(float v) {
#pragma unroll
    for (int off = 32; off > 0; off >>= 1) v += __shfl_xor(v, off);
    return v;
}

__global__ __launch_bounds__(256) void softmax2_kernel(
    float* __restrict__ score, const int* __restrict__ mask,
    const float* __restrict__ wei, bf16* __restrict__ scoreb)
{
    __shared__ float sred[4];
    const int row = blockIdx.x;
    const int t   = threadIdx.x;
    const size_t base = (size_t)row * NKK;
    const int wv = t >> 6, ln = t & 63;

    float l[16], w[16];
    unsigned mb = 0;
#pragma unroll
    for (int s = 0; s < 16; s++) {
        const int j = t + (s << 8);
        l[s] = score[base + j];
        w[s] = wei[base + j];
        if (mask[base + j] != 0) mb |= 1u << s;
    }

    float mx = -__builtin_inff();
#pragma unroll
    for (int s = 0; s < 16; s++) if (mb & (1u << s)) mx = fmaxf(mx, l[s]);
    mx = wred_max(mx);
    if (ln == 0) sred[wv] = mx;
    __syncthreads();
    mx = fmaxf(fmaxf(sred[0], sred[1]), fmaxf(sred[2], sred[3]));
    __syncthreads();
    float sum = 0.f;
#pragma unroll
    for (int s = 0; s < 16; s++) {
        const float e = (mb & (1u << s)) ? __expf(l[s] - mx) : 0.f;
        l[s] = e; sum += e;
    }
    sum = wred_sum(sum);
    if (ln == 0) sred[wv] = sum;
    __syncthreads();
    sum = sred[0] + sred[1] + sred[2] + sred[3];
    __syncthreads();
    const float inv1 = 1.0f / sum;

#pragma unroll
    for (int s = 0; s < 16; s++) l[s] = l[s] * inv1 * w[s];

    float mx2 = -__builtin_inff();
#pragma unroll
    for (int s = 0; s < 16; s++) if (mb & (1u << s)) mx2 = fmaxf(mx2, l[s]);
    mx2 = wred_max(mx2);
    if (ln == 0) sred[wv] = mx2;
    __syncthreads();
    mx2 = fmaxf(fmaxf(sred[0], sred[1]), fmaxf(sred[2], sred[3]));
    __syncthreads();
    float sum2 = 0.f;
#pragma unroll
    for (int s = 0; s < 16; s++) {
        const float e = (mb & (1u << s)) ? __expf(l[s] - mx2) : 0.f;
        l[s] = e; sum2 += e;
    }
    sum2 = wred_sum(sum2);
    if (ln == 0) sred[wv] = sum2;
    __syncthreads();
    sum2 = sred[0] + sred[1] + sred[2] + sred[3];
    const float inv2 = 1.0f / sum2;

#pragma unroll
    for (int s = 0; s < 16; s++) {
        const int j = t + (s << 8);
        const float p = l[s] * inv2;
        score[base + j]  = p;
        scoreb[base + j] = (bf16)p;
    }
}

// ---------------------------------------------------------------------------
extern "C" void kernel_launch(void* const* d_in, const int* in_sizes, int n_in,
                              void* d_out, int out_size, void* d_ws, size_t ws_size,
                              hipStream_t stream)
{
    (void)in_sizes; (void)n_in; (void)out_size;
    const float* q    = (const float*)d_in[0];
    const float* k    = (const float*)d_in[1];
    const int*   mask = (const int*)  d_in[2];
    const float* wei  = (const float*)d_in[3];
    const float* Wq   = (const float*)d_in[4];
    const float* bq   = (const float*)d_in[5];
    const float* Wk   = (const float*)d_in[6];
    const float* bk   = (const float*)d_in[7];
    const float* Wp   = (const float*)d_in[8];
    const float* bp   = (const float*)d_in[9];

    float* out   = (float*)d_out;
    float* score = (float*)d_out + (size_t)NQ * EMB;

    char* ws = (char*)d_ws;
    size_t off = 0;
    auto alloc = [&](size_t bytes) -> char* {
        char* p = ws + off; off += (bytes + 255) & ~(size_t)255; return p;
    };
    const size_t n_qk = (size_t)NQ * EMB;
    const size_t n_w  = (size_t)EMB * EMB;
    const size_t n_sc = (size_t)NQ * NKK;

    bf16* qh   = (bf16*)alloc(n_qk * 2);
    bf16* ql   = (bf16*)alloc(n_qk * 2);
    bf16* kh   = (bf16*)alloc(n_qk * 2);
    bf16* kl   = (bf16*)alloc(n_qk * 2);
    bf16* qxh  = (bf16*)alloc(n_qk * 2);
    bf16* qxl  = (bf16*)alloc(n_qk * 2);
    bf16* kxh  = (bf16*)alloc(n_qk * 2);
    bf16* kxl  = (bf16*)alloc(n_qk * 2);
    bf16* Wqh  = (bf16*)alloc(n_w * 2);
    bf16* Wql  = (bf16*)alloc(n_w * 2);
    bf16* Wkh  = (bf16*)alloc(n_w * 2);
    bf16* Wkl  = (bf16*)alloc(n_w * 2);
    bf16* Wpb  = (bf16*)alloc(n_w * 2);
    bf16* Wpl  = (bf16*)alloc(n_w * 2);
    bf16* kxTb = (bf16*)alloc(n_qk * 2);
    bf16* ctxb = (bf16*)alloc(n_qk * 2);
    bf16* scoreb = (bf16*)alloc(n_sc * 2);
    const size_t base_off = off;
    float* P = (float*)alloc(2 * n_qk * 4);   // 33.5 MB partials (split-K=2)
    const bool ws_ok = (off <= ws_size);
    if (base_off > ws_size) return;

    const int MN = (int)n_qk;

    // 1) prep
    prep_pair<<<dim3(n_qk / 1024, 2), 256, 0, stream>>>(q, k, qh, ql, kh, kl, (int)n_qk);
    prep_w3<<<dim3(n_w / 1024, 3), 256, 0, stream>>>(
        Wq, Wk, Wp, Wqh, Wql, Wkh, Wkl, Wpb, Wpl, (int)n_w);

    // 2) projections: batched z=2, direct bias + hi/lo epilogue
    gemm_bt_split<1, 1, 1><<<dim3(EMB / BN, NQ / BM, 2), 256, 0, stream>>>(
        qh, ql, Wqh, Wql, bq, qxh, qxl,
        kh, kl, Wkh, Wkl, bk, kxh, kxl,
        nullptr, NQ, EMB, EMB);

    // 3) kx^T for ctx GEMM B-operand
    transpose_bf16<<<dim3(EMB / 32, NKK / 32), 256, 0, stream>>>(kxh, kxTb, NKK, EMB);

    // 4) score logits = qx kx^T (4x2-tile split kernel, fp32 into d_out)
    gemm_score<<<dim3(NKK / 256, NQ / 128), 256, 0, stream>>>(
        qxh, qxl, kxh, kxl, score, NKK, EMB);

    // 5) fused double softmax
    softmax2_kernel<<<dim3(NQ), 256, 0, stream>>>(score, mask, wei, scoreb);

    // 6) ctx = p2 @ kx  (split-K=2)
    if (ws_ok) {
        gemm_bt<2, 0, 0><<<dim3(EMB / BN, NQ / BM, 2), 256, 0, stream>>>(
            scoreb, kxTb, nullptr, P, nullptr, NQ, EMB, NKK / 2, NKK, NKK);
        reduce_k<2, 0><<<dim3(MN / 1024), 256, 0, stream>>>(
            P, nullptr, nullptr, ctxb, MN, EMB);
    } else {
        gemm_bt<0, 0, 1><<<dim3(EMB / BN, NQ / BM), 256, 0, stream>>>(
            scoreb, kxTb, nullptr, nullptr, ctxb, NQ, EMB, NKK, NKK, NKK);
    }

    // 7) out = ctx @ Wp^T + bp  (split-K=2)
    if (ws_ok) {
        gemm_bt<2, 0, 0><<<dim3(EMB / BN, NQ / BM, 2), 256, 0, stream>>>(
            ctxb, Wpb, nullptr, P, nullptr, NQ, EMB, EMB / 2, EMB, EMB);
        reduce_k<2, 1><<<dim3(MN / 1024), 256, 0, stream>>>(
            P, bp, out, nullptr, MN, EMB);
    } else {
        gemm_bt<0, 1, 0><<<dim3(EMB / BN, NQ / BM), 256, 0, stream>>>(
            ctxb, Wpb, bp, out, nullptr, NQ, EMB, EMB, EMB, EMB);
    }
}